// Round 1
// baseline (887.629 us; speedup 1.0000x reference)
//
#include <hip/hip_runtime.h>
#include <hip/hip_bf16.h>
#include <stdint.h>

#define D_IN   4096
#define D_OUT  4096
#define MROWS  8192   // B*S = 4*2048
#define CAPN   1024

typedef __bf16 bf16x8 __attribute__((ext_vector_type(8)));
typedef float f32x4 __attribute__((ext_vector_type(4)));

// ---------- async global->LDS helper (16B per lane, uniform LDS base) ----------
__device__ static inline void async_copy16(const void* g, void* l) {
  __builtin_amdgcn_global_load_lds((__attribute__((address_space(1))) void*)g,
                                   (__attribute__((address_space(3))) void*)l,
                                   16, 0, 0);
}

// ---------- x fp32 -> bf16 ----------
__global__ __launch_bounds__(256) void cvt_x_kernel(const float* __restrict__ x,
                                                    __hip_bfloat16* __restrict__ xb) {
  size_t i = ((size_t)blockIdx.x * 256 + threadIdx.x) * 8;
  float4 f0 = *(const float4*)(x + i);
  float4 f1 = *(const float4*)(x + i + 4);
  union { __hip_bfloat16 h[8]; uint4 u; } o;
  o.h[0] = __float2bfloat16(f0.x); o.h[1] = __float2bfloat16(f0.y);
  o.h[2] = __float2bfloat16(f0.z); o.h[3] = __float2bfloat16(f0.w);
  o.h[4] = __float2bfloat16(f1.x); o.h[5] = __float2bfloat16(f1.y);
  o.h[6] = __float2bfloat16(f1.z); o.h[7] = __float2bfloat16(f1.w);
  *(uint4*)(xb + i) = o.u;
}

// ---------- dequant W: bf16(wl[o][i] * scale[o]) ----------
__global__ __launch_bounds__(256) void cvt_w_kernel(const float* __restrict__ wl,
                                                    const float* __restrict__ wscale,
                                                    __hip_bfloat16* __restrict__ wb) {
  size_t i = ((size_t)blockIdx.x * 256 + threadIdx.x) * 8;
  int row = (int)(i >> 12);             // D_IN = 4096 per row
  float s = wscale[row];
  float4 f0 = *(const float4*)(wl + i);
  float4 f1 = *(const float4*)(wl + i + 4);
  union { __hip_bfloat16 h[8]; uint4 u; } o;
  o.h[0] = __float2bfloat16(f0.x * s); o.h[1] = __float2bfloat16(f0.y * s);
  o.h[2] = __float2bfloat16(f0.z * s); o.h[3] = __float2bfloat16(f0.w * s);
  o.h[4] = __float2bfloat16(f1.x * s); o.h[5] = __float2bfloat16(f1.y * s);
  o.h[6] = __float2bfloat16(f1.z * s); o.h[7] = __float2bfloat16(f1.w * s);
  *(uint4*)(wb + i) = o.u;
}

// ---------- logits[c] = mem_keys[c,:] . q  (q = x[0,0,:], fp32) ----------
__global__ __launch_bounds__(256) void mem_logits_kernel(const float* __restrict__ keys,
                                                         const float* __restrict__ q,
                                                         float* __restrict__ logits) {
  int c = blockIdx.x;
  const float* k = keys + (size_t)c * D_IN;
  float p = 0.f;
  for (int i = threadIdx.x; i < D_IN; i += 256) p += k[i] * q[i];
  for (int off = 32; off; off >>= 1) p += __shfl_down(p, off);
  __shared__ float r[4];
  if ((threadIdx.x & 63) == 0) r[threadIdx.x >> 6] = p;
  __syncthreads();
  if (threadIdx.x == 0) logits[c] = r[0] + r[1] + r[2] + r[3];
}

// ---------- softmax over 1024 logits (one block, 1024 threads) ----------
__global__ __launch_bounds__(1024) void softmax_kernel(const float* __restrict__ logits,
                                                       float* __restrict__ attn) {
  int t = threadIdx.x;
  float v = logits[t];
  float m = v;
  for (int off = 32; off; off >>= 1) m = fmaxf(m, __shfl_down(m, off));
  __shared__ float wm[16];
  __shared__ float smax, ssum;
  if ((t & 63) == 0) wm[t >> 6] = m;
  __syncthreads();
  if (t == 0) {
    float mm = wm[0];
    for (int i = 1; i < 16; i++) mm = fmaxf(mm, wm[i]);
    smax = mm;
  }
  __syncthreads();
  float e = __expf(v - smax);
  float s = e;
  for (int off = 32; off; off >>= 1) s += __shfl_down(s, off);
  __shared__ float wsum[16];
  if ((t & 63) == 0) wsum[t >> 6] = s;
  __syncthreads();
  if (t == 0) {
    float ss = 0.f;
    for (int i = 0; i < 16; i++) ss += wsum[i];
    ssum = ss;
  }
  __syncthreads();
  attn[t] = e / ssum;
}

// ---------- memory_out[o] = sum_c attn[c] * mem_values[c,o] ----------
__global__ __launch_bounds__(256) void mem_out_kernel(const float* __restrict__ attn,
                                                      const float* __restrict__ vals,
                                                      float* __restrict__ memo) {
  int o = blockIdx.x * 256 + threadIdx.x;
  float acc = 0.f;
  for (int c = 0; c < CAPN; c++) acc += attn[c] * vals[(size_t)c * D_OUT + o];
  memo[o] = acc;
}

// ---------- main GEMM: C[m][n] = sum_k A[m][k]*W[n][k] + 0.01*memo[n] ----------
// m97 structure: 128x128 block tile, BK=32, 4 waves (2x2), 16x16x32 bf16 MFMA,
// global_load_lds width 16, LDS in fragment order (lane-linear ds_read_b128).
__global__ __launch_bounds__(256) void gemm_bt_kernel(const __hip_bfloat16* __restrict__ A,
                                                      const __hip_bfloat16* __restrict__ Bm,
                                                      const float* __restrict__ memo,
                                                      float* __restrict__ C) {
  __shared__ bf16x8 As[512];   // 8 m-tiles x 64 frags (frag = [kq(4)][m(16)])
  __shared__ bf16x8 Bs[512];   // 8 n-tiles x 64 frags
  const int tid = threadIdx.x;
  const int l = tid & 63;
  const int w = tid >> 6;
  const int m_blk = blockIdx.y * 128;
  const int n_blk = blockIdx.x * 128;

  const int lm = l & 15;          // row within 16-row tile for staging
  const int lk = (l >> 4) * 8;    // k offset for staging (0,8,16,24)

  // wave w stages m-tiles {w, w+4} of A and n-tiles {w, w+4} of B
  const __hip_bfloat16* gA0 = A  + (size_t)(m_blk + (w    ) * 16 + lm) * D_IN + lk;
  const __hip_bfloat16* gA1 = A  + (size_t)(m_blk + (w + 4) * 16 + lm) * D_IN + lk;
  const __hip_bfloat16* gB0 = Bm + (size_t)(n_blk + (w    ) * 16 + lm) * D_IN + lk;
  const __hip_bfloat16* gB1 = Bm + (size_t)(n_blk + (w + 4) * 16 + lm) * D_IN + lk;
  bf16x8* lA0 = &As[(w    ) * 64];
  bf16x8* lA1 = &As[(w + 4) * 64];
  bf16x8* lB0 = &Bs[(w    ) * 64];
  bf16x8* lB1 = &Bs[(w + 4) * 64];

  const int wm = (w >> 1) * 4;    // wave's m-tile base (compute)
  const int wn = (w & 1) * 4;     // wave's n-tile base (compute)

  f32x4 acc[4][4] = {};

  for (int k0 = 0; k0 < D_IN; k0 += 32) {
    async_copy16(gA0 + k0, lA0);
    async_copy16(gA1 + k0, lA1);
    async_copy16(gB0 + k0, lB0);
    async_copy16(gB1 + k0, lB1);
    __syncthreads();              // drains vmcnt -> LDS tile complete

    bf16x8 a[4], b[4];
#pragma unroll
    for (int i = 0; i < 4; i++) a[i] = As[(wm + i) * 64 + l];
#pragma unroll
    for (int j = 0; j < 4; j++) b[j] = Bs[(wn + j) * 64 + l];
#pragma unroll
    for (int i = 0; i < 4; i++)
#pragma unroll
      for (int j = 0; j < 4; j++)
        acc[i][j] = __builtin_amdgcn_mfma_f32_16x16x32_bf16(a[i], b[j], acc[i][j], 0, 0, 0);

    __syncthreads();              // protect LDS before next overwrite
  }

  // epilogue: D mapping col = l&15, row = (l>>4)*4 + r
  const int col_l = l & 15;
  const int row_l = (l >> 4) * 4;
#pragma unroll
  for (int j = 0; j < 4; j++) {
    int col = n_blk + (wn + j) * 16 + col_l;
    float mo = 0.01f * memo[col];
#pragma unroll
    for (int i = 0; i < 4; i++) {
      int row = m_blk + (wm + i) * 16 + row_l;
      float* cp = C + (size_t)row * D_OUT + col;
#pragma unroll
      for (int r = 0; r < 4; r++) cp[(size_t)r * D_OUT] = acc[i][j][r] + mo;
    }
  }
}

extern "C" void kernel_launch(void* const* d_in, const int* in_sizes, int n_in,
                              void* d_out, int out_size, void* d_ws, size_t ws_size,
                              hipStream_t stream) {
  const float* x   = (const float*)d_in[0];   // [4,2048,4096]
  const float* wl  = (const float*)d_in[1];   // [4096,4096]
  const float* wsc = (const float*)d_in[2];   // [4096,1]
  const float* mk  = (const float*)d_in[3];   // [1024,4096]
  const float* mv  = (const float*)d_in[4];   // [1024,4096]
  float* out = (float*)d_out;                 // [4,2048,4096] fp32

  char* wsb = (char*)d_ws;
  __hip_bfloat16* xb = (__hip_bfloat16*)wsb;                                    // 67,108,864 B
  __hip_bfloat16* wb = (__hip_bfloat16*)(wsb + (size_t)MROWS * D_IN * 2);       // 33,554,432 B
  float* logits = (float*)(wsb + (size_t)MROWS * D_IN * 2 + (size_t)D_OUT * D_IN * 2);
  float* attn = logits + CAPN;
  float* memo = attn + CAPN;                                                    // 4096 floats

  // conversions (independent of mem path; all serialized on stream)
  cvt_x_kernel<<<dim3((MROWS * D_IN) / 2048), dim3(256), 0, stream>>>(x, xb);
  cvt_w_kernel<<<dim3((D_OUT * D_IN) / 2048), dim3(256), 0, stream>>>(wl, wsc, wb);

  // associative-memory path (q = x[0,0,:], fp32 throughout)
  mem_logits_kernel<<<dim3(CAPN), dim3(256), 0, stream>>>(mk, x, logits);
  softmax_kernel<<<dim3(1), dim3(1024), 0, stream>>>(logits, attn);
  mem_out_kernel<<<dim3(D_OUT / 256), dim3(256), 0, stream>>>(attn, mv, memo);

  // main GEMM + fused memory_out epilogue
  gemm_bt_kernel<<<dim3(D_OUT / 128, MROWS / 128), dim3(256), 0, stream>>>(xb, wb, memo, out);
}

// Round 2
// 779.827 us; speedup vs baseline: 1.1382x; 1.1382x over previous
//
#include <hip/hip_runtime.h>
#include <hip/hip_bf16.h>
#include <stdint.h>

#define D_IN   4096
#define D_OUT  4096
#define MROWS  8192   // B*S = 4*2048
#define CAPN   1024

typedef __bf16 bf16x8 __attribute__((ext_vector_type(8)));
typedef float f32x4 __attribute__((ext_vector_type(4)));

// ---------- async global->LDS helper (16B per lane, uniform LDS base) ----------
__device__ static inline void async_copy16(const void* g, void* l) {
  __builtin_amdgcn_global_load_lds((__attribute__((address_space(1))) void*)g,
                                   (__attribute__((address_space(3))) void*)l,
                                   16, 0, 0);
}

// ---------- x fp32 -> bf16 ----------
__global__ __launch_bounds__(256) void cvt_x_kernel(const float* __restrict__ x,
                                                    __hip_bfloat16* __restrict__ xb) {
  size_t i = ((size_t)blockIdx.x * 256 + threadIdx.x) * 8;
  float4 f0 = *(const float4*)(x + i);
  float4 f1 = *(const float4*)(x + i + 4);
  union { __hip_bfloat16 h[8]; uint4 u; } o;
  o.h[0] = __float2bfloat16(f0.x); o.h[1] = __float2bfloat16(f0.y);
  o.h[2] = __float2bfloat16(f0.z); o.h[3] = __float2bfloat16(f0.w);
  o.h[4] = __float2bfloat16(f1.x); o.h[5] = __float2bfloat16(f1.y);
  o.h[6] = __float2bfloat16(f1.z); o.h[7] = __float2bfloat16(f1.w);
  *(uint4*)(xb + i) = o.u;
}

// ---------- dequant W: bf16(wl[o][i] * scale[o]) ----------
__global__ __launch_bounds__(256) void cvt_w_kernel(const float* __restrict__ wl,
                                                    const float* __restrict__ wscale,
                                                    __hip_bfloat16* __restrict__ wb) {
  size_t i = ((size_t)blockIdx.x * 256 + threadIdx.x) * 8;
  int row = (int)(i >> 12);             // D_IN = 4096 per row
  float s = wscale[row];
  float4 f0 = *(const float4*)(wl + i);
  float4 f1 = *(const float4*)(wl + i + 4);
  union { __hip_bfloat16 h[8]; uint4 u; } o;
  o.h[0] = __float2bfloat16(f0.x * s); o.h[1] = __float2bfloat16(f0.y * s);
  o.h[2] = __float2bfloat16(f0.z * s); o.h[3] = __float2bfloat16(f0.w * s);
  o.h[4] = __float2bfloat16(f1.x * s); o.h[5] = __float2bfloat16(f1.y * s);
  o.h[6] = __float2bfloat16(f1.z * s); o.h[7] = __float2bfloat16(f1.w * s);
  *(uint4*)(wb + i) = o.u;
}

// ---------- logits[c] = mem_keys[c,:] . q  (q = x[0,0,:], fp32) ----------
__global__ __launch_bounds__(256) void mem_logits_kernel(const float* __restrict__ keys,
                                                         const float* __restrict__ q,
                                                         float* __restrict__ logits) {
  int c = blockIdx.x;
  const float* k = keys + (size_t)c * D_IN;
  float p = 0.f;
  for (int i = threadIdx.x; i < D_IN; i += 256) p += k[i] * q[i];
  for (int off = 32; off; off >>= 1) p += __shfl_down(p, off);
  __shared__ float r[4];
  if ((threadIdx.x & 63) == 0) r[threadIdx.x >> 6] = p;
  __syncthreads();
  if (threadIdx.x == 0) logits[c] = r[0] + r[1] + r[2] + r[3];
}

// ---------- softmax over 1024 logits (one block, 1024 threads) ----------
__global__ __launch_bounds__(1024) void softmax_kernel(const float* __restrict__ logits,
                                                       float* __restrict__ attn) {
  int t = threadIdx.x;
  float v = logits[t];
  float m = v;
  for (int off = 32; off; off >>= 1) m = fmaxf(m, __shfl_down(m, off));
  __shared__ float wm[16];
  __shared__ float smax, ssum;
  if ((t & 63) == 0) wm[t >> 6] = m;
  __syncthreads();
  if (t == 0) {
    float mm = wm[0];
    for (int i = 1; i < 16; i++) mm = fmaxf(mm, wm[i]);
    smax = mm;
  }
  __syncthreads();
  float e = __expf(v - smax);
  float s = e;
  for (int off = 32; off; off >>= 1) s += __shfl_down(s, off);
  __shared__ float wsum[16];
  if ((t & 63) == 0) wsum[t >> 6] = s;
  __syncthreads();
  if (t == 0) {
    float ss = 0.f;
    for (int i = 0; i < 16; i++) ss += wsum[i];
    ssum = ss;
  }
  __syncthreads();
  attn[t] = e / ssum;
}

// ---------- memo[o] += sum_{c in block-chunk} attn[c] * vals[c,o] ----------
// 2D grid: x = o-chunk (16 blocks x 256), y = c-chunk (16 blocks x 64).
// memo zero-initialized via hipMemsetAsync; device-scope atomicAdd combines.
__global__ __launch_bounds__(256) void mem_out_kernel(const float* __restrict__ attn,
                                                      const float* __restrict__ vals,
                                                      float* __restrict__ memo) {
  int o = blockIdx.x * 256 + threadIdx.x;
  int c0 = blockIdx.y * 64;
  float acc = 0.f;
#pragma unroll 8
  for (int c = c0; c < c0 + 64; c++) acc += attn[c] * vals[(size_t)c * D_OUT + o];
  atomicAdd(&memo[o], acc);
}

// ---------- main GEMM: C[m][n] = sum_k A[m][k]*W[n][k] + 0.01*memo[n] ----------
// 128x128 tile, BK=32, 4 waves (2x2), 16x16x32 bf16 MFMA, global_load_lds w16.
// Double-buffered LDS, ONE barrier per K-iter, prefetch issued one iter ahead
// (after the barrier + frag reads) so the vmcnt(0) drain inside __syncthreads
// overlaps a full MFMA block instead of exposing raw load latency.
__global__ __launch_bounds__(256) void gemm_bt_kernel(const __hip_bfloat16* __restrict__ A,
                                                      const __hip_bfloat16* __restrict__ Bm,
                                                      const float* __restrict__ memo,
                                                      float* __restrict__ C) {
  __shared__ bf16x8 As[2][512];   // per buf: 8 m-tiles x 64 frags (frag = [kq(4)][m(16)])
  __shared__ bf16x8 Bs[2][512];
  const int tid = threadIdx.x;
  const int l = tid & 63;
  const int w = tid >> 6;
  const int m_blk = blockIdx.y * 128;
  const int n_blk = blockIdx.x * 128;

  const int lm = l & 15;          // row within 16-row tile for staging
  const int lk = (l >> 4) * 8;    // k offset for staging (0,8,16,24)

  // wave w stages m-tiles {w, w+4} of A and n-tiles {w, w+4} of B
  const __hip_bfloat16* gA0 = A  + (size_t)(m_blk + w * 16 + lm) * D_IN + lk;
  const __hip_bfloat16* gA1 = gA0 + (size_t)64 * D_IN;
  const __hip_bfloat16* gB0 = Bm + (size_t)(n_blk + w * 16 + lm) * D_IN + lk;
  const __hip_bfloat16* gB1 = gB0 + (size_t)64 * D_IN;

  const int wm = (w >> 1) * 4;    // wave's m-tile base (compute)
  const int wn = (w & 1) * 4;     // wave's n-tile base (compute)

  // prologue: stage K-tile 0 into buf 0
  async_copy16(gA0, &As[0][w * 64]);
  async_copy16(gA1, &As[0][(w + 4) * 64]);
  async_copy16(gB0, &Bs[0][w * 64]);
  async_copy16(gB1, &Bs[0][(w + 4) * 64]);

  f32x4 acc[4][4] = {};

  for (int k0 = 0; k0 < D_IN / 32; ++k0) {
    const int c = k0 & 1;
    __syncthreads();   // drains this iter's loads (issued 1 iter ago) + prev ds_reads

    bf16x8 a[4], b[4];
#pragma unroll
    for (int i = 0; i < 4; i++) a[i] = As[c][(wm + i) * 64 + l];
#pragma unroll
    for (int j = 0; j < 4; j++) b[j] = Bs[c][(wn + j) * 64 + l];

    if (k0 + 1 < D_IN / 32) {     // prefetch next K-tile into the other buffer
      const int nb = c ^ 1;
      const int koff = (k0 + 1) * 32;
      async_copy16(gA0 + koff, &As[nb][w * 64]);
      async_copy16(gA1 + koff, &As[nb][(w + 4) * 64]);
      async_copy16(gB0 + koff, &Bs[nb][w * 64]);
      async_copy16(gB1 + koff, &Bs[nb][(w + 4) * 64]);
    }

#pragma unroll
    for (int i = 0; i < 4; i++)
#pragma unroll
      for (int j = 0; j < 4; j++)
        acc[i][j] = __builtin_amdgcn_mfma_f32_16x16x32_bf16(a[i], b[j], acc[i][j], 0, 0, 0);
  }

  // epilogue: D mapping col = l&15, row = (l>>4)*4 + r
  const int col_l = l & 15;
  const int row_l = (l >> 4) * 4;
#pragma unroll
  for (int j = 0; j < 4; j++) {
    int col = n_blk + (wn + j) * 16 + col_l;
    float mo = 0.01f * memo[col];
#pragma unroll
    for (int i = 0; i < 4; i++) {
      int row = m_blk + (wm + i) * 16 + row_l;
      float* cp = C + (size_t)row * D_OUT + col;
#pragma unroll
      for (int r = 0; r < 4; r++) cp[(size_t)r * D_OUT] = acc[i][j][r] + mo;
    }
  }
}

extern "C" void kernel_launch(void* const* d_in, const int* in_sizes, int n_in,
                              void* d_out, int out_size, void* d_ws, size_t ws_size,
                              hipStream_t stream) {
  const float* x   = (const float*)d_in[0];   // [4,2048,4096]
  const float* wl  = (const float*)d_in[1];   // [4096,4096]
  const float* wsc = (const float*)d_in[2];   // [4096,1]
  const float* mk  = (const float*)d_in[3];   // [1024,4096]
  const float* mv  = (const float*)d_in[4];   // [1024,4096]
  float* out = (float*)d_out;                 // [4,2048,4096] fp32

  char* wsb = (char*)d_ws;
  __hip_bfloat16* xb = (__hip_bfloat16*)wsb;                                    // 67,108,864 B
  __hip_bfloat16* wb = (__hip_bfloat16*)(wsb + (size_t)MROWS * D_IN * 2);       // 33,554,432 B
  float* logits = (float*)(wsb + (size_t)MROWS * D_IN * 2 + (size_t)D_OUT * D_IN * 2);
  float* attn = logits + CAPN;
  float* memo = attn + CAPN;                                                    // 4096 floats

  // conversions (independent of mem path; all serialized on stream)
  cvt_x_kernel<<<dim3((MROWS * D_IN) / 2048), dim3(256), 0, stream>>>(x, xb);
  cvt_w_kernel<<<dim3((D_OUT * D_IN) / 2048), dim3(256), 0, stream>>>(wl, wsc, wb);

  // associative-memory path (q = x[0,0,:], fp32 throughout)
  mem_logits_kernel<<<dim3(CAPN), dim3(256), 0, stream>>>(mk, x, logits);
  softmax_kernel<<<dim3(1), dim3(1024), 0, stream>>>(logits, attn);
  hipMemsetAsync(memo, 0, D_OUT * sizeof(float), stream);
  mem_out_kernel<<<dim3(D_OUT / 256, 16), dim3(256), 0, stream>>>(attn, mv, memo);

  // main GEMM + fused memory_out epilogue
  gemm_bt_kernel<<<dim3(D_OUT / 128, MROWS / 128), dim3(256), 0, stream>>>(xb, wb, memo, out);
}